// Round 1
// baseline (317.397 us; speedup 1.0000x reference)
//
#include <hip/hip_runtime.h>
#include <hip/hip_bf16.h>

typedef __attribute__((ext_vector_type(8))) short short8;
typedef __attribute__((ext_vector_type(4))) float floatx4;

#define MFMA16(a, b, c) __builtin_amdgcn_mfma_f32_16x16x32_bf16((a), (b), (c), 0, 0, 0)

__device__ __forceinline__ unsigned short f2bf(float x) {
  union { float f; unsigned u; } v; v.f = x;
  unsigned r = v.u + 0x7FFFu + ((v.u >> 16) & 1u);  // RNE
  return (unsigned short)(r >> 16);
}

__device__ __forceinline__ short8 ld8(const unsigned short* p) {
  return *reinterpret_cast<const short8*>(p);
}

// ---------------- fp32 -> bf16 convert (vectorized) ----------------
__global__ void k_f32_to_bf16(const float* __restrict__ in,
                              unsigned short* __restrict__ out, int n4) {
  int i = blockIdx.x * blockDim.x + threadIdx.x;
  if (i >= n4) return;
  float4 f = reinterpret_cast<const float4*>(in)[i];
  union { unsigned short u[4]; unsigned long long v; } o;
  o.u[0] = f2bf(f.x); o.u[1] = f2bf(f.y); o.u[2] = f2bf(f.z); o.u[3] = f2bf(f.w);
  reinterpret_cast<unsigned long long*>(out)[i] = o.v;
}

// ---------------- transpose + convert: out[c][r] = bf16(in[r][c]) ----------------
// in: [R][C] fp32, out: [C][R] bf16. block (64,4), grid (C/64, R/64).
__global__ void k_transpose_bf16(const float* __restrict__ in,
                                 unsigned short* __restrict__ out, int R, int C) {
  __shared__ float tile[64][65];
  int c0 = blockIdx.x * 64, r0 = blockIdx.y * 64;
  int tx = threadIdx.x, ty = threadIdx.y;
  for (int i = ty; i < 64; i += 4)
    tile[i][tx] = in[(size_t)(r0 + i) * C + c0 + tx];
  __syncthreads();
  for (int i = ty; i < 64; i += 4)
    out[(size_t)(c0 + i) * R + r0 + tx] = f2bf(tile[tx][i]);
}

// ---------------- GEMM: C[M,N] = A[M,K] @ W[K,N], W given transposed (Bt[N,K]) ----
// A, Bt bf16 row-major. 128x128 tile per 256-thread block, 4 waves in 2x2,
// each wave 64x64 = 4x4 16x16x32 MFMA frags. BK=32.
template <int OUT_BF16, int HAS_BIAS>
__global__ __launch_bounds__(256) void k_gemm_bt(
    const unsigned short* __restrict__ A, const unsigned short* __restrict__ Bt,
    void* __restrict__ Cout, const float* __restrict__ bias, int M, int N, int K) {
  __shared__ unsigned short As[128][40];  // +8 pad keeps 16B align, spreads banks
  __shared__ unsigned short Bs[128][40];
  int tid = threadIdx.x;
  int w = tid >> 6, lane = tid & 63, quad = lane >> 4, l16 = lane & 15;
  int wy = w >> 1, wx = w & 1;
  int rowB = blockIdx.y * 128, colB = blockIdx.x * 128;

  floatx4 acc[4][4];
  floatx4 zero4 = {0.f, 0.f, 0.f, 0.f};
#pragma unroll
  for (int mi = 0; mi < 4; ++mi)
#pragma unroll
    for (int ni = 0; ni < 4; ++ni) acc[mi][ni] = zero4;

  for (int kt = 0; kt < K; kt += 32) {
    __syncthreads();
    // stage 128x32 of A and Bt: 512 chunks of 8 bf16, 2 per thread
#pragma unroll
    for (int i = tid; i < 512; i += 256) {
      int r = i >> 2, c = (i & 3) << 3;
      *reinterpret_cast<short8*>(&As[r][c]) =
          ld8(&A[(size_t)(rowB + r) * K + kt + c]);
      *reinterpret_cast<short8*>(&Bs[r][c]) =
          ld8(&Bt[(size_t)(colB + r) * K + kt + c]);
    }
    __syncthreads();
    short8 af[4], bf_[4];
#pragma unroll
    for (int mi = 0; mi < 4; ++mi)
      af[mi] = ld8(&As[wy * 64 + mi * 16 + l16][quad * 8]);
#pragma unroll
    for (int ni = 0; ni < 4; ++ni)
      bf_[ni] = ld8(&Bs[wx * 64 + ni * 16 + l16][quad * 8]);
#pragma unroll
    for (int mi = 0; mi < 4; ++mi)
#pragma unroll
      for (int ni = 0; ni < 4; ++ni)
        acc[mi][ni] = MFMA16(af[mi], bf_[ni], acc[mi][ni]);
  }

  // epilogue: C/D layout col=lane&15, row=quad*4+reg
#pragma unroll
  for (int mi = 0; mi < 4; ++mi) {
    int row = rowB + wy * 64 + mi * 16 + quad * 4;
#pragma unroll
    for (int ni = 0; ni < 4; ++ni) {
      int col = colB + wx * 64 + ni * 16 + l16;
      float bv = HAS_BIAS ? bias[col] : 0.f;
#pragma unroll
      for (int r = 0; r < 4; ++r) {
        float val = acc[mi][ni][r] + bv;
        if (OUT_BF16)
          ((unsigned short*)Cout)[(size_t)(row + r) * N + col] = f2bf(val);
        else
          ((float*)Cout)[(size_t)(row + r) * N + col] = val;
      }
    }
  }
}

// ---------------- flash attention, causal ----------------
// qkv: [B*T][3072] bf16 (q|k|v each 1024 wide, head h at h*64).
// grid: (T/64, B*H), block 256 (4 waves). Wave w owns q rows [q0+16w, q0+16w+15].
__global__ __launch_bounds__(256) void k_attn(
    const unsigned short* __restrict__ qkv, unsigned short* __restrict__ attn_out) {
  const int T = 2048, LD = 3072;
  __shared__ unsigned short Kt[64][72];      // [key][d]  (+8 pad, 16B-mult stride)
  __shared__ unsigned short Vt[64][72];      // [d][key]  (V transposed)
  __shared__ unsigned short Pt[4][16][72];   // per-wave P [q][key]

  int bh = blockIdx.y, b = bh >> 4, h = bh & 15;
  int q0 = blockIdx.x * 64;
  const unsigned short* base = qkv + (size_t)b * T * LD;
  const unsigned short* Qp = base + h * 64;
  const unsigned short* Kp = base + 1024 + h * 64;
  const unsigned short* Vp = base + 2048 + h * 64;
  int tid = threadIdx.x, w = tid >> 6, lane = tid & 63;
  int quad = lane >> 4, l16 = lane & 15;

  // Q fragments in registers (A-layout: m=l16 within wave's 16 rows, k=quad*8+j)
  short8 aq[2];
  {
    const unsigned short* qrow = Qp + (size_t)(q0 + w * 16 + l16) * LD + quad * 8;
    aq[0] = ld8(qrow);
    aq[1] = ld8(qrow + 32);
  }

  float m_i[4], l_i[4];
  floatx4 o_acc[4];
  floatx4 zero4 = {0.f, 0.f, 0.f, 0.f};
#pragma unroll
  for (int r = 0; r < 4; ++r) { m_i[r] = -1e30f; l_i[r] = 0.f; }
#pragma unroll
  for (int nd = 0; nd < 4; ++nd) o_acc[nd] = zero4;

  int nfull = q0 >> 6;  // tiles 0..nfull-1 unmasked, nfull = diagonal tile
  for (int kt = 0; kt <= nfull; ++kt) {
    __syncthreads();
    for (int i = tid; i < 4096; i += 256) {
      int key = i >> 6, d = i & 63;
      size_t goff = (size_t)(kt * 64 + key) * LD + d;
      Kt[key][d] = Kp[goff];
      Vt[d][key] = Vp[goff];
    }
    __syncthreads();

    // S = Q K^T (16q x 64key per wave), C/D layout
    floatx4 s[4];
#pragma unroll
    for (int nk = 0; nk < 4; ++nk) {
      short8 bk0 = ld8(&Kt[nk * 16 + l16][quad * 8]);
      short8 bk1 = ld8(&Kt[nk * 16 + l16][32 + quad * 8]);
      s[nk] = MFMA16(aq[0], bk0, zero4);
      s[nk] = MFMA16(aq[1], bk1, s[nk]);
    }

    bool diag = (kt == nfull);
    const float scale = 0.125f;  // 1/sqrt(64)
#pragma unroll
    for (int nk = 0; nk < 4; ++nk)
#pragma unroll
      for (int r = 0; r < 4; ++r) {
        float sv = s[nk][r] * scale;
        if (diag && (nk * 16 + l16 > w * 16 + quad * 4 + r)) sv = -1e30f;
        s[nk][r] = sv;
      }

    // online softmax per q-row; the 16 lanes of a quad hold one row's 64 keys
    float alpha[4];
#pragma unroll
    for (int r = 0; r < 4; ++r) {
      float tm = fmaxf(fmaxf(s[0][r], s[1][r]), fmaxf(s[2][r], s[3][r]));
      tm = fmaxf(tm, __shfl_xor(tm, 1));
      tm = fmaxf(tm, __shfl_xor(tm, 2));
      tm = fmaxf(tm, __shfl_xor(tm, 4));
      tm = fmaxf(tm, __shfl_xor(tm, 8));
      float mn = fmaxf(m_i[r], tm);
      alpha[r] = __expf(m_i[r] - mn);
      m_i[r] = mn;
      float rs = 0.f;
#pragma unroll
      for (int nk = 0; nk < 4; ++nk) {
        float p = __expf(s[nk][r] - mn);
        s[nk][r] = p;
        rs += p;
      }
      rs += __shfl_xor(rs, 1);
      rs += __shfl_xor(rs, 2);
      rs += __shfl_xor(rs, 4);
      rs += __shfl_xor(rs, 8);
      l_i[r] = l_i[r] * alpha[r] + rs;
    }

    // P -> LDS (bf16, per-wave buffer), rescale O
#pragma unroll
    for (int nk = 0; nk < 4; ++nk)
#pragma unroll
      for (int r = 0; r < 4; ++r)
        Pt[w][quad * 4 + r][nk * 16 + l16] = f2bf(s[nk][r]);
#pragma unroll
    for (int nd = 0; nd < 4; ++nd)
#pragma unroll
      for (int r = 0; r < 4; ++r) o_acc[nd][r] *= alpha[r];

    __syncthreads();  // conservative: ensure Pt writes visible to whole wave

    // O += P V  (P in A-layout from LDS; Vt rows give B-layout n=d)
    short8 pa0 = ld8(&Pt[w][l16][quad * 8]);
    short8 pa1 = ld8(&Pt[w][l16][32 + quad * 8]);
#pragma unroll
    for (int nd = 0; nd < 4; ++nd) {
      short8 bv0 = ld8(&Vt[nd * 16 + l16][quad * 8]);
      short8 bv1 = ld8(&Vt[nd * 16 + l16][32 + quad * 8]);
      o_acc[nd] = MFMA16(pa0, bv0, o_acc[nd]);
      o_acc[nd] = MFMA16(pa1, bv1, o_acc[nd]);
    }
  }

  // epilogue: attn_out [B*T][1024] bf16
#pragma unroll
  for (int nd = 0; nd < 4; ++nd)
#pragma unroll
    for (int r = 0; r < 4; ++r) {
      int q = q0 + w * 16 + quad * 4 + r;
      int d = nd * 16 + l16;
      attn_out[(size_t)(b * T + q) * 1024 + h * 64 + d] =
          f2bf(o_acc[nd][r] / l_i[r]);
    }
}

extern "C" void kernel_launch(void* const* d_in, const int* in_sizes, int n_in,
                              void* d_out, int out_size, void* d_ws, size_t ws_size,
                              hipStream_t stream) {
  const float* x = (const float*)d_in[0];       // [2,2048,1024]
  const float* w_qkv = (const float*)d_in[1];   // [1024,3072]
  const float* w_proj = (const float*)d_in[2];  // [1024,1024]
  const float* b_proj = (const float*)d_in[3];  // [1024]
  float* out = (float*)d_out;                   // [2,2048,1024] fp32

  char* ws = (char*)d_ws;
  unsigned short* xb     = (unsigned short*)(ws);                     // 8 MB
  unsigned short* wqkvT  = (unsigned short*)(ws + (size_t)(8  << 20)); // 6 MB
  unsigned short* wprojT = (unsigned short*)(ws + (size_t)(14 << 20)); // 2 MB
  unsigned short* qkvb   = (unsigned short*)(ws + (size_t)(16 << 20)); // 24 MB
  unsigned short* attnb  = (unsigned short*)(ws + (size_t)(40 << 20)); // 8 MB

  k_f32_to_bf16<<<4096, 256, 0, stream>>>(x, xb, (4096 * 1024) / 4);
  dim3 tb(64, 4);
  k_transpose_bf16<<<dim3(3072 / 64, 1024 / 64), tb, 0, stream>>>(w_qkv, wqkvT, 1024, 3072);
  k_transpose_bf16<<<dim3(1024 / 64, 1024 / 64), tb, 0, stream>>>(w_proj, wprojT, 1024, 1024);
  k_gemm_bt<1, 0><<<dim3(3072 / 128, 4096 / 128), 256, 0, stream>>>(
      xb, wqkvT, qkvb, nullptr, 4096, 3072, 1024);
  k_attn<<<dim3(2048 / 64, 2 * 16), 256, 0, stream>>>(qkvb, attnb);
  k_gemm_bt<0, 1><<<dim3(1024 / 128, 4096 / 128), 256, 0, stream>>>(
      attnb, wprojT, out, b_proj, 4096, 1024, 1024);
}